// Round 2
// baseline (1897.875 us; speedup 1.0000x reference)
//
#include <hip/hip_runtime.h>
#include <hip/hip_bf16.h>
#include <float.h>

#define NSLOPE 0.2f

// ---------------- sum of squares per point ----------------
__global__ __launch_bounds__(256) void sumsq_kernel(const float* __restrict__ X, int ldx, int C,
                                                    float* __restrict__ xx, int total) {
  int t = blockIdx.x * 256 + threadIdx.x;
  if (t >= total) return;
  const float* p = X + (size_t)t * ldx;
  float s = 0.f;
  for (int c = 0; c < C; ++c) { float v = p[c]; s += v * v; }
  xx[t] = s;
}

// ---------------- combined-weight prep: Wc[c, j<cout]=W_a ; Wc[c, j>=cout]=W_b - W_a ----------------
__global__ __launch_bounds__(256) void wcprep_kernel(const float* __restrict__ W, int cin, int cout,
                                                     float* __restrict__ Wc) {
  int t = blockIdx.x * 256 + threadIdx.x;
  int tot = cin * 2 * cout;
  if (t >= tot) return;
  int c = t / (2 * cout), j = t % (2 * cout);
  float v;
  if (j < cout) v = W[c * cout + j];
  else          v = W[(cin + c) * cout + (j - cout)] - W[c * cout + (j - cout)];
  Wc[t] = v;
}

// ---------------- generic fp32 GEMM: C(M x N) = A(M x K, lda) * B(K x N, ldb) ----------------
__global__ __launch_bounds__(256) void gemm_kernel(const float* __restrict__ A, int lda,
                                                   const float* __restrict__ Bm, int ldb,
                                                   float* __restrict__ C, int ldc,
                                                   int M, int N, int K) {
  __shared__ float As[16][65];
  __shared__ float Bs[16][64];
  int tid = threadIdx.x;
  int tx = tid & 15, ty = tid >> 4;   // ty -> row, tx -> col (coalesced C store)
  int row0 = blockIdx.y * 64, col0 = blockIdx.x * 64;
  float acc[4][4] = {};
  for (int k0 = 0; k0 < K; k0 += 16) {
    {
      int c = tid & 15, r4 = tid >> 4;
#pragma unroll
      for (int j = 0; j < 4; ++j) {
        int r = r4 + j * 16;
        float v = 0.f;
        if (k0 + c < K) v = A[(size_t)(row0 + r) * lda + k0 + c];
        As[c][r] = v;
      }
    }
    {
      int n = tid & 63, c4 = tid >> 6;
#pragma unroll
      for (int j = 0; j < 4; ++j) {
        int c = c4 + j * 4;
        float v = 0.f;
        if (k0 + c < K) v = Bm[(size_t)(k0 + c) * ldb + col0 + n];
        Bs[c][n] = v;
      }
    }
    __syncthreads();
#pragma unroll
    for (int kk = 0; kk < 16; ++kk) {
      float a[4], b[4];
#pragma unroll
      for (int i = 0; i < 4; ++i) a[i] = As[kk][ty * 4 + i];
#pragma unroll
      for (int j = 0; j < 4; ++j) b[j] = Bs[kk][tx * 4 + j];
#pragma unroll
      for (int i = 0; i < 4; ++i)
#pragma unroll
        for (int j = 0; j < 4; ++j) acc[i][j] += a[i] * b[j];
    }
    __syncthreads();
  }
#pragma unroll
  for (int i = 0; i < 4; ++i)
#pragma unroll
    for (int j = 0; j < 4; ++j)
      C[(size_t)(row0 + ty * 4 + i) * ldc + col0 + tx * 4 + j] = acc[i][j];
}

// ---------------- neg-dist: D[n,m] = 2*X_n.X_m - xx_n - xx_m (per batch slice) ----------------
__global__ __launch_bounds__(256) void dist_kernel(const float* __restrict__ X, int ldx, int C,
                                                   const float* __restrict__ xx, float* __restrict__ D,
                                                   int b0, int N) {
  int batch = b0 + blockIdx.z;
  const float* Xb = X + (size_t)batch * N * ldx;
  const float* xxb = xx + (size_t)batch * N;
  float* Db = D + (size_t)blockIdx.z * N * N;
  __shared__ float Qs[16][65];
  __shared__ float Ps[16][65];
  int tid = threadIdx.x;
  int tx = tid & 15, ty = tid >> 4;
  int n0 = blockIdx.y * 64, m0 = blockIdx.x * 64;
  float acc[4][4] = {};
  for (int k0 = 0; k0 < C; k0 += 16) {
    int c = tid & 15, r4 = tid >> 4;
#pragma unroll
    for (int j = 0; j < 4; ++j) {
      int r = r4 + j * 16;
      float q = 0.f, p = 0.f;
      if (k0 + c < C) {
        q = Xb[(size_t)(n0 + r) * ldx + k0 + c];
        p = Xb[(size_t)(m0 + r) * ldx + k0 + c];
      }
      Qs[c][r] = q; Ps[c][r] = p;
    }
    __syncthreads();
#pragma unroll
    for (int kk = 0; kk < 16; ++kk) {
      float a[4], b[4];
#pragma unroll
      for (int i = 0; i < 4; ++i) a[i] = Qs[kk][ty * 4 + i];
#pragma unroll
      for (int j = 0; j < 4; ++j) b[j] = Ps[kk][tx * 4 + j];
#pragma unroll
      for (int i = 0; i < 4; ++i)
#pragma unroll
        for (int j = 0; j < 4; ++j) acc[i][j] += a[i] * b[j];
    }
    __syncthreads();
  }
#pragma unroll
  for (int i = 0; i < 4; ++i) {
    int n = n0 + ty * 4 + i;
    float xn = xxb[n];
#pragma unroll
    for (int j = 0; j < 4; ++j) {
      int m = m0 + tx * 4 + j;
      Db[(size_t)n * N + m] = 2.f * acc[i][j] - xn - xxb[m];
    }
  }
}

// ---------------- top-K (largest neg-dist, ties -> lower index) ----------------
__global__ __launch_bounds__(256) void topk_kernel(const float* __restrict__ D, int* __restrict__ idxo,
                                                   int b0, int N, int Ktop) {
  int n = blockIdx.x;
  int bz = blockIdx.y;
  int batch = b0 + bz;
  const float* row = D + (size_t)bz * N * N + (size_t)n * N;
  int tid = threadIdx.x;
  unsigned long long keys[8];
#pragma unroll
  for (int j = 0; j < 8; ++j) {
    int m = tid + j * 256;
    float d = row[m];
    unsigned u = __float_as_uint(d);
    u = (u & 0x80000000u) ? ~u : (u | 0x80000000u);
    keys[j] = ((unsigned long long)u << 32) | (unsigned)(N - 1 - m);
  }
  __shared__ unsigned long long wred[4];
  __shared__ unsigned long long winls;
  int* out = idxo + ((size_t)batch * N + n) * Ktop;
  for (int k = 0; k < Ktop; ++k) {
    unsigned long long loc = keys[0];
#pragma unroll
    for (int j = 1; j < 8; ++j) loc = keys[j] > loc ? keys[j] : loc;
#pragma unroll
    for (int off = 32; off >= 1; off >>= 1) {
      unsigned long long o = __shfl_down(loc, off, 64);
      if (o > loc) loc = o;
    }
    if ((tid & 63) == 0) wred[tid >> 6] = loc;
    __syncthreads();
    if (tid == 0) {
      unsigned long long w = wred[0];
      for (int j = 1; j < 4; ++j) if (wred[j] > w) w = wred[j];
      winls = w;
      out[k] = N - 1 - (int)(unsigned)(w & 0xFFFFFFFFu);
    }
    __syncthreads();
    unsigned long long w = winls;
#pragma unroll
    for (int j = 0; j < 8; ++j) if (keys[j] == w) keys[j] = 0ull;
    __syncthreads();
  }
}

// ---------------- gather + max over K + scale/bias/leaky ----------------
__global__ __launch_bounds__(256) void gathermax_kernel(const float* __restrict__ YZ, int ldyz, int cout,
                                                        const int* __restrict__ idxo,
                                                        const float* __restrict__ g, const float* __restrict__ bias,
                                                        float* __restrict__ outp, int ldo, int N, int Ktop,
                                                        int total) {
  int t = blockIdx.x * 256 + threadIdx.x;
  if (t >= total) return;
  int d = t % cout;
  int bn = t / cout;     // b*N + n
  int b = bn / N;
  const int* ip = idxo + (size_t)bn * Ktop;
  float gv = g[d];
  float zv = YZ[(size_t)bn * ldyz + cout + d];
  bool pos = gv >= 0.f;
  float best = pos ? -FLT_MAX : FLT_MAX;
  for (int k = 0; k < Ktop; ++k) {
    int m = ip[k];
    float yv = YZ[((size_t)b * N + m) * ldyz + d];
    best = pos ? fmaxf(best, yv) : fminf(best, yv);
  }
  float h = (best + zv) * gv + bias[d];
  outp[(size_t)bn * ldo + d] = h >= 0.f ? h : NSLOPE * h;
}

// ---------------- final GEMM (512->1024) + g/b/leaky + transposed store ----------------
__global__ __launch_bounds__(256) void gemm_out_kernel(const float* __restrict__ A,
                                                       const float* __restrict__ W,
                                                       const float* __restrict__ g, const float* __restrict__ bias,
                                                       float* __restrict__ outp,
                                                       int M, int N, int K, int Npts) {
  __shared__ float As[16][65];
  __shared__ float Bs[16][64];
  int tid = threadIdx.x;
  int tx = tid & 15, ty = tid >> 4;   // tx -> row (n, coalesced transposed store), ty -> col (d)
  int row0 = blockIdx.y * 64, col0 = blockIdx.x * 64;
  float acc[4][4] = {};
  for (int k0 = 0; k0 < K; k0 += 16) {
    {
      int c = tid & 15, r4 = tid >> 4;
#pragma unroll
      for (int j = 0; j < 4; ++j) {
        int r = r4 + j * 16;
        float v = 0.f;
        if (k0 + c < K) v = A[(size_t)(row0 + r) * K + k0 + c];
        As[c][r] = v;
      }
    }
    {
      int n = tid & 63, c4 = tid >> 6;
#pragma unroll
      for (int j = 0; j < 4; ++j) {
        int c = c4 + j * 4;
        float v = 0.f;
        if (k0 + c < K) v = W[(size_t)(k0 + c) * N + col0 + n];
        Bs[c][n] = v;
      }
    }
    __syncthreads();
#pragma unroll
    for (int kk = 0; kk < 16; ++kk) {
      float a[4], b[4];
#pragma unroll
      for (int i = 0; i < 4; ++i) a[i] = As[kk][tx * 4 + i];
#pragma unroll
      for (int j = 0; j < 4; ++j) b[j] = Bs[kk][ty * 4 + j];
#pragma unroll
      for (int i = 0; i < 4; ++i)
#pragma unroll
        for (int j = 0; j < 4; ++j) acc[i][j] += a[i] * b[j];
    }
    __syncthreads();
  }
  int batch = row0 / Npts;
  int nl0 = (row0 % Npts) + tx * 4;
#pragma unroll
  for (int j = 0; j < 4; ++j) {
    int d = col0 + ty * 4 + j;
    float gv = g[d], bv = bias[d];
    float4 v;
    float h;
    h = acc[0][j] * gv + bv; v.x = h >= 0.f ? h : NSLOPE * h;
    h = acc[1][j] * gv + bv; v.y = h >= 0.f ? h : NSLOPE * h;
    h = acc[2][j] * gv + bv; v.z = h >= 0.f ? h : NSLOPE * h;
    h = acc[3][j] * gv + bv; v.w = h >= 0.f ? h : NSLOPE * h;
    *(float4*)(outp + ((size_t)batch * N + d) * Npts + nl0) = v;
  }
}

extern "C" void kernel_launch(void* const* d_in, const int* in_sizes, int n_in,
                              void* d_out, int out_size, void* d_ws, size_t ws_size,
                              hipStream_t stream) {
  const int B = 8, N = 2048, Ktop = 20;
  const int M = B * N;  // 16384

  const float* pts = (const float*)d_in[0];
  const float* W1 = (const float*)d_in[1];  const float* g1 = (const float*)d_in[2];  const float* b1 = (const float*)d_in[3];
  const float* W2 = (const float*)d_in[4];  const float* g2 = (const float*)d_in[5];  const float* b2 = (const float*)d_in[6];
  const float* W3 = (const float*)d_in[7];  const float* g3 = (const float*)d_in[8];  const float* b3 = (const float*)d_in[9];
  const float* W4 = (const float*)d_in[10]; const float* g4 = (const float*)d_in[11]; const float* b4 = (const float*)d_in[12];
  const float* W5 = (const float*)d_in[13]; const float* g5 = (const float*)d_in[14]; const float* b5 = (const float*)d_in[15];

  float* p = (float*)d_ws;
  float* XC = p;  p += (size_t)M * 512;        // concat feature buffer [x1|x2|x3|x4]
  float* Wc = p;  p += 128 * 512;              // combined weight, max cin*2cout
  float* xx = p;  p += M;                      // per-point sum of squares
  int* idxb = (int*)p; p = (float*)(idxb + (size_t)M * Ktop);
  float* shared = p;                           // D and YZ overlap (disjoint lifetimes)
  size_t shared_bytes = ws_size - (size_t)((char*)shared - (char*)d_ws);
  float* D = shared;
  float* YZ = shared;
  int chunk = (int)(shared_bytes / ((size_t)N * N * sizeof(float)));
  if (chunk > B) chunk = B;
  if (chunk < 1) chunk = 1;

  auto knn = [&](const float* Xp, int ldx, int C) {
    sumsq_kernel<<<(M + 255) / 256, 256, 0, stream>>>(Xp, ldx, C, xx, M);
    for (int b0 = 0; b0 < B; b0 += chunk) {
      int nb = (B - b0 < chunk) ? (B - b0) : chunk;
      dist_kernel<<<dim3(N / 64, N / 64, nb), 256, 0, stream>>>(Xp, ldx, C, xx, D, b0, N);
      topk_kernel<<<dim3(N, nb), 256, 0, stream>>>(D, idxb, b0, N, Ktop);
    }
  };

  auto econv = [&](const float* Xp, int ldx, int cin, int cout,
                   const float* W, const float* g, const float* bb, float* outp) {
    int tot = cin * 2 * cout;
    wcprep_kernel<<<(tot + 255) / 256, 256, 0, stream>>>(W, cin, cout, Wc);
    gemm_kernel<<<dim3(2 * cout / 64, M / 64), 256, 0, stream>>>(Xp, ldx, Wc, 2 * cout, YZ, 2 * cout, M, 2 * cout, cin);
    int total = B * N * cout;
    gathermax_kernel<<<(total + 255) / 256, 256, 0, stream>>>(YZ, 2 * cout, cout, idxb, g, bb, outp, 512, N, Ktop, total);
  };

  // layer 1: x (pts, 3ch) -> x1 (64) at XC col 0
  knn(pts, 3, 3);
  econv(pts, 3, 3, 64, W1, g1, b1, XC + 0);
  // layer 2: x1 -> x2 (64) at XC col 64
  knn(XC + 0, 512, 64);
  econv(XC + 0, 512, 64, 64, W2, g2, b2, XC + 64);
  // layer 3: x2 -> x3 (128) at XC col 128
  knn(XC + 64, 512, 64);
  econv(XC + 64, 512, 64, 128, W3, g3, b3, XC + 128);
  // layer 4: x3 -> x4 (256) at XC col 256
  knn(XC + 128, 512, 128);
  econv(XC + 128, 512, 128, 256, W4, g4, b4, XC + 256);
  // final: cat(512) @ W5 -> (B,1024,N)
  gemm_out_kernel<<<dim3(1024 / 64, M / 64), 256, 0, stream>>>(XC, W5, g5, b5, (float*)d_out, M, 1024, 512, N);
}